// Round 1
// baseline (1316.024 us; speedup 1.0000x reference)
//
#include <hip/hip_runtime.h>
#include <math.h>

// ---------------- helpers ----------------
__device__ __forceinline__ float wsum(float v) {
  #pragma unroll
  for (int o = 32; o > 0; o >>= 1) v += __shfl_xor(v, o, 64);
  return v;
}

// ---------------- embed: y = relu(LN(x@W + b) * g + beta) ----------------
// one 64-lane wave per node row; lane = output dim
__global__ void embed_kernel(const float* __restrict__ x, const float* __restrict__ W,
                             const float* __restrict__ b, const float* __restrict__ g,
                             const float* __restrict__ beta, float* __restrict__ y,
                             int N, int FD) {
  int gid  = blockIdx.x * blockDim.x + threadIdx.x;
  int wid  = gid >> 6;
  int lane = gid & 63;
  if (wid >= N) return;
  const float* xr = x + (size_t)wid * FD;
  float acc = b[lane];
  for (int k = 0; k < FD; ++k) acc = fmaf(xr[k], W[k * 64 + lane], acc);
  float m = wsum(acc) * (1.f / 64.f);
  float d = acc - m;
  float v = wsum(d * d) * (1.f / 64.f);
  float o = d * rsqrtf(v + 1e-5f) * g[lane] + beta[lane];
  y[(size_t)wid * 64 + lane] = fmaxf(o, 0.f);
}

// ---------------- generic zero ----------------
__global__ void zero_kernel(unsigned int* __restrict__ p, long long n) {
  long long i  = (long long)blockIdx.x * blockDim.x + threadIdx.x;
  long long st = (long long)gridDim.x * blockDim.x;
  for (; i < n; i += st) p[i] = 0u;
}

// ---------------- CSR build ----------------
__global__ void count_kernel(const int* __restrict__ ei, int E, int* __restrict__ cnt) {
  int e = blockIdx.x * blockDim.x + threadIdx.x;
  if (e < E) atomicAdd(&cnt[ei[E + e]], 1);
}

// single-block exclusive scan; reads counts from cnt_next, writes row_ptr and
// resets cnt_next to the running offsets (for fill)
__global__ void scan_kernel(int* __restrict__ cnt_next, int* __restrict__ row_ptr, int n) {
  __shared__ int lds[1024];
  __shared__ int carry;
  int tid = threadIdx.x;
  if (tid == 0) carry = 0;
  __syncthreads();
  for (int base = 0; base < n; base += 1024) {
    int i = base + tid;
    int v = (i < n) ? cnt_next[i] : 0;
    lds[tid] = v;
    __syncthreads();
    for (int o = 1; o < 1024; o <<= 1) {
      int t = (tid >= o) ? lds[tid - o] : 0;
      __syncthreads();
      lds[tid] += t;
      __syncthreads();
    }
    int exc = carry + lds[tid] - v;  // read carry before update
    if (i < n) { row_ptr[i] = exc; cnt_next[i] = exc; }
    int tot = lds[1023];
    __syncthreads();
    if (tid == 0) carry += tot;
    __syncthreads();
  }
  if (tid == 0) row_ptr[n] = carry;
}

__global__ void fill_kernel(const int* __restrict__ ei, int E,
                            int* __restrict__ next, int* __restrict__ col) {
  int e = blockIdx.x * blockDim.x + threadIdx.x;
  if (e >= E) return;
  int s = ei[e], d = ei[E + e];
  int pos = atomicAdd(&next[d], 1);
  col[pos] = s;
}

// ---------------- GEMM: Y[N,256] = X[N,64] @ W[64,256] ----------------
template <int RPB>
__global__ __launch_bounds__(256) void gemm_kernel(const float* __restrict__ X,
                                                   const float* __restrict__ W,
                                                   float* __restrict__ Y, int N) {
  __shared__ float Ws[64 * 256];   // 64 KB
  __shared__ float Xs[RPB][64];
  int tid = threadIdx.x;
  for (int i = tid; i < 64 * 256; i += 256) Ws[i] = W[i];
  int r0 = blockIdx.x * RPB;
  for (int i = tid; i < RPB * 64; i += 256) {
    int r = i >> 6, c = i & 63;
    Xs[r][c] = (r0 + r < N) ? X[(size_t)(r0 + r) * 64 + c] : 0.f;
  }
  __syncthreads();
  float acc[RPB];
  #pragma unroll
  for (int r = 0; r < RPB; ++r) acc[r] = 0.f;
  for (int k = 0; k < 64; k += 4) {
    float w0 = Ws[(k + 0) * 256 + tid];
    float w1 = Ws[(k + 1) * 256 + tid];
    float w2 = Ws[(k + 2) * 256 + tid];
    float w3 = Ws[(k + 3) * 256 + tid];
    #pragma unroll
    for (int r = 0; r < RPB; ++r) {
      float4 xv = *(const float4*)&Xs[r][k];
      acc[r] = fmaf(xv.x, w0, fmaf(xv.y, w1, fmaf(xv.z, w2, fmaf(xv.w, w3, acc[r]))));
    }
  }
  #pragma unroll
  for (int r = 0; r < RPB; ++r)
    if (r0 + r < N) Y[(size_t)(r0 + r) * 256 + tid] = acc[r];
}

// ---------------- GATv2 per-dst-node: wave per node ----------------
__global__ void gat_kernel(const float* __restrict__ xl, const float* __restrict__ xr,
                           const int* __restrict__ rowp, const int* __restrict__ col,
                           const float* __restrict__ att, const float* __restrict__ bias,
                           float* __restrict__ logits, float* __restrict__ agg, int Nd) {
  int gid  = blockIdx.x * blockDim.x + threadIdx.x;
  int n    = gid >> 6;
  int lane = gid & 63;
  if (n >= Nd) return;
  int beg = rowp[n], end = rowp[n + 1];
  const float* xrp = xr + (size_t)n * 256;
  float x0 = xrp[lane], x1 = xrp[64 + lane], x2 = xrp[128 + lane], x3 = xrp[192 + lane];
  float a0 = att[lane], a1 = att[64 + lane], a2 = att[128 + lane], a3 = att[192 + lane];
  float m0 = -3e38f, m1 = -3e38f, m2 = -3e38f, m3 = -3e38f;
  // pass 1: logits + max
  for (int i = beg; i < end; ++i) {
    int s = col[i];
    const float* xs = xl + (size_t)s * 256;
    float v0 = x0 + xs[lane];
    float v1 = x1 + xs[64 + lane];
    float v2 = x2 + xs[128 + lane];
    float v3 = x3 + xs[192 + lane];
    v0 = v0 > 0.f ? v0 : 0.2f * v0;
    v1 = v1 > 0.f ? v1 : 0.2f * v1;
    v2 = v2 > 0.f ? v2 : 0.2f * v2;
    v3 = v3 > 0.f ? v3 : 0.2f * v3;
    float l0 = wsum(v0 * a0), l1 = wsum(v1 * a1), l2 = wsum(v2 * a2), l3 = wsum(v3 * a3);
    if (lane == 0) {
      float4 lg = make_float4(l0, l1, l2, l3);
      *(float4*)&logits[(size_t)i * 4] = lg;
    }
    m0 = fmaxf(m0, l0); m1 = fmaxf(m1, l1); m2 = fmaxf(m2, l2); m3 = fmaxf(m3, l3);
  }
  // pass 2: exp / denom / weighted sum
  float d0 = 0.f, d1 = 0.f, d2 = 0.f, d3 = 0.f;
  float c0 = 0.f, c1 = 0.f, c2 = 0.f, c3 = 0.f;
  for (int i = beg; i < end; ++i) {
    int s = col[i];
    float4 lg = *(const float4*)&logits[(size_t)i * 4];
    float e0 = __expf(lg.x - m0), e1 = __expf(lg.y - m1);
    float e2 = __expf(lg.z - m2), e3 = __expf(lg.w - m3);
    d0 += e0; d1 += e1; d2 += e2; d3 += e3;
    const float* xs = xl + (size_t)s * 256;
    c0 = fmaf(e0, xs[lane],       c0);
    c1 = fmaf(e1, xs[64 + lane],  c1);
    c2 = fmaf(e2, xs[128 + lane], c2);
    c3 = fmaf(e3, xs[192 + lane], c3);
  }
  float o = 0.f;
  if (end > beg) o = 0.25f * (c0 / d0 + c1 / d1 + c2 / d2 + c3 / d3);
  agg[(size_t)n * 64 + lane] += o + bias[lane];
}

// ---------------- combine: x = relu(agg) + x ----------------
__global__ void combine_kernel(const float* __restrict__ agg, const float* __restrict__ xin,
                               float* __restrict__ xout, int n) {
  int i = blockIdx.x * blockDim.x + threadIdx.x;
  if (i < n) xout[i] = fmaxf(agg[i], 0.f) + xin[i];
}

// ---------------- pool: mean & max per node type ----------------
// gc layout: [s_mean, t_mean, w_mean, s_max, t_max, w_max] (64 each)
__global__ void pool_kernel(const float* __restrict__ xt, const float* __restrict__ xw,
                            const float* __restrict__ xs, float* __restrict__ gc) {
  const float* x; int N; int mi;
  if (blockIdx.x == 0)      { x = xs; N = 1000;  mi = 0;   }
  else if (blockIdx.x == 1) { x = xt; N = 20000; mi = 64;  }
  else                      { x = xw; N = 5000;  mi = 128; }
  int lane = threadIdx.x & 63, w = threadIdx.x >> 6;
  float s = 0.f, mx = -3e38f;
  for (int r = w; r < N; r += 16) {
    float v = x[(size_t)r * 64 + lane];
    s += v; mx = fmaxf(mx, v);
  }
  __shared__ float ss[16][64];
  __shared__ float sm[16][64];
  ss[w][lane] = s; sm[w][lane] = mx;
  __syncthreads();
  if (w == 0) {
    #pragma unroll
    for (int i = 1; i < 16; ++i) { s += ss[i][lane]; mx = fmaxf(mx, sm[i][lane]); }
    gc[mi + lane] = s / (float)N;
    gc[192 + mi + lane] = mx;
  }
}

// ---------------- driver ----------------
extern "C" void kernel_launch(void* const* d_in, const int* in_sizes, int n_in,
                              void* d_out, int out_size, void* d_ws, size_t ws_size,
                              hipStream_t stream) {
  const float* x_in[3] = {(const float*)d_in[0], (const float*)d_in[1], (const float*)d_in[2]};
  const int*   ei[5]   = {(const int*)d_in[3], (const int*)d_in[4], (const int*)d_in[5],
                          (const int*)d_in[6], (const int*)d_in[7]};
  const float* Wemb[3] = {(const float*)d_in[8],  (const float*)d_in[12], (const float*)d_in[16]};
  const float* bemb[3] = {(const float*)d_in[9],  (const float*)d_in[13], (const float*)d_in[17]};
  const float* gemb[3] = {(const float*)d_in[10], (const float*)d_in[14], (const float*)d_in[18]};
  const float* beemb[3]= {(const float*)d_in[11], (const float*)d_in[15], (const float*)d_in[19]};
  const float* gWl   = (const float*)d_in[20];
  const float* gWr   = (const float*)d_in[21];
  const float* gatt  = (const float*)d_in[22];
  const float* gbias = (const float*)d_in[23];

  const int NN[3]  = {20000, 5000, 1000};   // task, worker, station
  const int FD[3]  = {16, 12, 10};
  const int EC[5]  = {50000, 30000, 30000, 40000, 40000};
  const int STy[5] = {0, 0, 2, 1, 0};
  const int DTy[5] = {0, 2, 0, 0, 1};

  char* p = (char*)d_ws;
  auto alloc = [&](size_t bytes) -> void* {
    void* r = (void*)p;
    p += (bytes + 255) & ~(size_t)255;
    return r;
  };
  float* xc[3];
  for (int k = 0; k < 3; ++k) xc[k] = (float*)alloc((size_t)NN[k] * 64 * 4);
  float* aggBase = (float*)alloc((size_t)26000 * 64 * 4);
  float* agg[3] = {aggBase, aggBase + (size_t)20000 * 64, aggBase + (size_t)25000 * 64};
  float* xlb    = (float*)alloc((size_t)20000 * 256 * 4);
  float* xrb    = (float*)alloc((size_t)20000 * 256 * 4);
  float* logits = (float*)alloc((size_t)50000 * 4 * 4);
  int *rowp[5], *nxt[5], *col[5];
  for (int t = 0; t < 5; ++t) {
    rowp[t] = (int*)alloc((size_t)(NN[DTy[t]] + 1) * 4);
    nxt[t]  = (int*)alloc((size_t)NN[DTy[t]] * 4);
    col[t]  = (int*)alloc((size_t)EC[t] * 4);
  }

  // 1) embedders
  for (int k = 0; k < 3; ++k) {
    int threads = NN[k] * 64;
    embed_kernel<<<(threads + 255) / 256, 256, 0, stream>>>(
        x_in[k], Wemb[k], bemb[k], gemb[k], beemb[k], xc[k], NN[k], FD[k]);
  }

  // 2) CSR per edge type (edges are layer-invariant)
  for (int t = 0; t < 5; ++t) {
    int Nd = NN[DTy[t]], E = EC[t];
    zero_kernel<<<64, 256, 0, stream>>>((unsigned*)nxt[t], Nd);
    count_kernel<<<(E + 255) / 256, 256, 0, stream>>>(ei[t], E, nxt[t]);
    scan_kernel<<<1, 1024, 0, stream>>>(nxt[t], rowp[t], Nd);
    fill_kernel<<<(E + 255) / 256, 256, 0, stream>>>(ei[t], E, nxt[t], col[t]);
  }

  float* outT = (float*)d_out;
  float* outW = outT + (size_t)20000 * 64;
  float* outS = outW + (size_t)5000 * 64;
  float* gc   = outS + (size_t)1000 * 64;

  // 3) GAT layers
  for (int l = 0; l < 2; ++l) {
    zero_kernel<<<512, 256, 0, stream>>>((unsigned*)aggBase, (long long)26000 * 64);
    for (int t = 0; t < 5; ++t) {
      int s = STy[t], dt = DTy[t];
      int Ns = NN[s], Nd = NN[dt];
      size_t off = (size_t)(l * 5 + t);
      gemm_kernel<16><<<(Ns + 15) / 16, 256, 0, stream>>>(xc[s],  gWl + off * 64 * 256, xlb, Ns);
      gemm_kernel<16><<<(Nd + 15) / 16, 256, 0, stream>>>(xc[dt], gWr + off * 64 * 256, xrb, Nd);
      gat_kernel<<<(Nd * 64 + 255) / 256, 256, 0, stream>>>(
          xlb, xrb, rowp[t], col[t], gatt + off * 256, gbias + off * 64,
          logits, agg[dt], Nd);
    }
    for (int k = 0; k < 3; ++k) {
      float* dst = (l == 1) ? (k == 0 ? outT : (k == 1 ? outW : outS)) : xc[k];
      int n = NN[k] * 64;
      combine_kernel<<<(n + 255) / 256, 256, 0, stream>>>(agg[k], xc[k], dst, n);
    }
  }

  // 4) global pooling
  pool_kernel<<<3, 1024, 0, stream>>>(outT, outW, outS, gc);
}

// Round 2
// 930.063 us; speedup vs baseline: 1.4150x; 1.4150x over previous
//
#include <hip/hip_runtime.h>
#include <math.h>

// ---------------- helpers ----------------
__device__ __forceinline__ float wsum(float v) {
  #pragma unroll
  for (int o = 32; o > 0; o >>= 1) v += __shfl_xor(v, o, 64);
  return v;
}

// ---------------- embed: y = relu(LN(x@W + b) * g + beta) ----------------
__global__ void embed_kernel(const float* __restrict__ x, const float* __restrict__ W,
                             const float* __restrict__ b, const float* __restrict__ g,
                             const float* __restrict__ beta, float* __restrict__ y,
                             int N, int FD) {
  int gid  = blockIdx.x * blockDim.x + threadIdx.x;
  int wid  = gid >> 6;
  int lane = gid & 63;
  if (wid >= N) return;
  const float* xr = x + (size_t)wid * FD;
  float acc = b[lane];
  for (int k = 0; k < FD; ++k) acc = fmaf(xr[k], W[k * 64 + lane], acc);
  float m = wsum(acc) * (1.f / 64.f);
  float d = acc - m;
  float v = wsum(d * d) * (1.f / 64.f);
  float o = d * rsqrtf(v + 1e-5f) * g[lane] + beta[lane];
  y[(size_t)wid * 64 + lane] = fmaxf(o, 0.f);
}

// ---------------- generic zero ----------------
__global__ void zero_kernel(unsigned int* __restrict__ p, long long n) {
  long long i  = (long long)blockIdx.x * blockDim.x + threadIdx.x;
  long long st = (long long)gridDim.x * blockDim.x;
  for (; i < n; i += st) p[i] = 0u;
}

// ---------------- CSR build ----------------
__global__ void count_kernel(const int* __restrict__ ei, int E, int* __restrict__ cnt) {
  int e = blockIdx.x * blockDim.x + threadIdx.x;
  if (e < E) atomicAdd(&cnt[ei[E + e]], 1);
}

// single-block exclusive scan (wave-shfl based); reads counts from cnt_next,
// writes row_ptr and resets cnt_next to the running offsets (for fill)
__global__ void scan_kernel(int* __restrict__ cnt_next, int* __restrict__ row_ptr, int n) {
  __shared__ int wsums[16];
  __shared__ int carry_s;
  int tid = threadIdx.x, lane = tid & 63, w = tid >> 6;
  if (tid == 0) carry_s = 0;
  __syncthreads();
  for (int base = 0; base < n; base += 1024) {
    int i = base + tid;
    int v = (i < n) ? cnt_next[i] : 0;
    int s = v;  // inclusive wave scan
    #pragma unroll
    for (int o = 1; o < 64; o <<= 1) { int t = __shfl_up(s, o, 64); if (lane >= o) s += t; }
    if (lane == 63) wsums[w] = s;
    __syncthreads();
    if (w == 0 && lane < 16) {
      int x = wsums[lane];
      #pragma unroll
      for (int o = 1; o < 16; o <<= 1) { int t = __shfl_up(x, o, 16); if (lane >= o) x += t; }
      wsums[lane] = x;
    }
    __syncthreads();
    int carry   = carry_s;
    int waveoff = (w == 0) ? 0 : wsums[w - 1];
    int exc     = carry + waveoff + s - v;
    if (i < n) { row_ptr[i] = exc; cnt_next[i] = exc; }
    __syncthreads();
    if (tid == 0) carry_s += wsums[15];
    __syncthreads();
  }
  if (threadIdx.x == 0) row_ptr[n] = carry_s;
}

__global__ void fill_kernel(const int* __restrict__ ei, int E,
                            int* __restrict__ next, int* __restrict__ col) {
  int e = blockIdx.x * blockDim.x + threadIdx.x;
  if (e >= E) return;
  int s = ei[e], d = ei[E + e];
  int pos = atomicAdd(&next[d], 1);
  col[pos] = s;
}

// ---------------- GEMM: Y[N,256] = X[N,64] @ W[64,256] ----------------
template <int RPB>
__global__ __launch_bounds__(256) void gemm_kernel(const float* __restrict__ X,
                                                   const float* __restrict__ W,
                                                   float* __restrict__ Y, int N) {
  __shared__ float Ws[64 * 256];   // 64 KB
  __shared__ float Xs[RPB][64];
  int tid = threadIdx.x;
  for (int i = tid; i < 64 * 256; i += 256) Ws[i] = W[i];
  int r0 = blockIdx.x * RPB;
  for (int i = tid; i < RPB * 64; i += 256) {
    int r = i >> 6, c = i & 63;
    Xs[r][c] = (r0 + r < N) ? X[(size_t)(r0 + r) * 64 + c] : 0.f;
  }
  __syncthreads();
  float acc[RPB];
  #pragma unroll
  for (int r = 0; r < RPB; ++r) acc[r] = 0.f;
  for (int k = 0; k < 64; k += 4) {
    float w0 = Ws[(k + 0) * 256 + tid];
    float w1 = Ws[(k + 1) * 256 + tid];
    float w2 = Ws[(k + 2) * 256 + tid];
    float w3 = Ws[(k + 3) * 256 + tid];
    #pragma unroll
    for (int r = 0; r < RPB; ++r) {
      float4 xv = *(const float4*)&Xs[r][k];
      acc[r] = fmaf(xv.x, w0, fmaf(xv.y, w1, fmaf(xv.z, w2, fmaf(xv.w, w3, acc[r]))));
    }
  }
  #pragma unroll
  for (int r = 0; r < RPB; ++r)
    if (r0 + r < N) Y[(size_t)(r0 + r) * 256 + tid] = acc[r];
}

// ---------------- GATv2 per-dst-node: wave per node ----------------
__global__ void gat_kernel(const float* __restrict__ xl, const float* __restrict__ xr,
                           const int* __restrict__ rowp, const int* __restrict__ col,
                           const float* __restrict__ att, const float* __restrict__ bias,
                           float* __restrict__ logits, float* __restrict__ agg, int Nd,
                           int accum) {
  int gid  = blockIdx.x * blockDim.x + threadIdx.x;
  int n    = gid >> 6;
  int lane = gid & 63;
  if (n >= Nd) return;
  int beg = rowp[n], end = rowp[n + 1];
  const float* xrp = xr + (size_t)n * 256;
  float x0 = xrp[lane], x1 = xrp[64 + lane], x2 = xrp[128 + lane], x3 = xrp[192 + lane];
  float a0 = att[lane], a1 = att[64 + lane], a2 = att[128 + lane], a3 = att[192 + lane];
  float m0 = -3e38f, m1 = -3e38f, m2 = -3e38f, m3 = -3e38f;
  for (int i = beg; i < end; ++i) {
    int s = col[i];
    const float* xs = xl + (size_t)s * 256;
    float v0 = x0 + xs[lane];
    float v1 = x1 + xs[64 + lane];
    float v2 = x2 + xs[128 + lane];
    float v3 = x3 + xs[192 + lane];
    v0 = v0 > 0.f ? v0 : 0.2f * v0;
    v1 = v1 > 0.f ? v1 : 0.2f * v1;
    v2 = v2 > 0.f ? v2 : 0.2f * v2;
    v3 = v3 > 0.f ? v3 : 0.2f * v3;
    float l0 = wsum(v0 * a0), l1 = wsum(v1 * a1), l2 = wsum(v2 * a2), l3 = wsum(v3 * a3);
    if (lane == 0) {
      float4 lg = make_float4(l0, l1, l2, l3);
      *(float4*)&logits[(size_t)i * 4] = lg;
    }
    m0 = fmaxf(m0, l0); m1 = fmaxf(m1, l1); m2 = fmaxf(m2, l2); m3 = fmaxf(m3, l3);
  }
  float d0 = 0.f, d1 = 0.f, d2 = 0.f, d3 = 0.f;
  float c0 = 0.f, c1 = 0.f, c2 = 0.f, c3 = 0.f;
  for (int i = beg; i < end; ++i) {
    int s = col[i];
    float4 lg = *(const float4*)&logits[(size_t)i * 4];
    float e0 = __expf(lg.x - m0), e1 = __expf(lg.y - m1);
    float e2 = __expf(lg.z - m2), e3 = __expf(lg.w - m3);
    d0 += e0; d1 += e1; d2 += e2; d3 += e3;
    const float* xs = xl + (size_t)s * 256;
    c0 = fmaf(e0, xs[lane],       c0);
    c1 = fmaf(e1, xs[64 + lane],  c1);
    c2 = fmaf(e2, xs[128 + lane], c2);
    c3 = fmaf(e3, xs[192 + lane], c3);
  }
  float o = 0.f;
  if (end > beg) o = 0.25f * (c0 / d0 + c1 / d1 + c2 / d2 + c3 / d3);
  float val = o + bias[lane];
  size_t idx = (size_t)n * 64 + lane;
  if (accum) agg[idx] += val; else agg[idx] = val;
}

// ---------------- combine: x = relu(agg) + x ----------------
__global__ void combine_kernel(const float* __restrict__ agg, const float* __restrict__ xin,
                               float* __restrict__ xout, int n) {
  int i = blockIdx.x * blockDim.x + threadIdx.x;
  if (i < n) xout[i] = fmaxf(agg[i], 0.f) + xin[i];
}

// ---------------- pool stage 1: per-block partial sum/max ----------------
// blocks 0..79 task, 80..99 worker, 100..103 station; 256 thr = 4 waves
__global__ __launch_bounds__(256) void pool1_kernel(const float* __restrict__ xt,
                                                    const float* __restrict__ xw,
                                                    const float* __restrict__ xs,
                                                    float* __restrict__ part_sum,
                                                    float* __restrict__ part_max) {
  int b = blockIdx.x;
  const float* x; int N, base, nb;
  if (b < 80)       { x = xt; N = 20000; base = 0;   nb = 80; }
  else if (b < 100) { x = xw; N = 5000;  base = 80;  nb = 20; }
  else              { x = xs; N = 1000;  base = 100; nb = 4;  }
  int local = b - base;
  int lane = threadIdx.x & 63, w = threadIdx.x >> 6;
  int waveIdx = local * 4 + w, stride = nb * 4;
  float s = 0.f, mx = -3e38f;
  for (int r = waveIdx; r < N; r += stride) {
    float v = x[(size_t)r * 64 + lane];
    s += v; mx = fmaxf(mx, v);
  }
  __shared__ float ss[4][64], sm[4][64];
  ss[w][lane] = s; sm[w][lane] = mx;
  __syncthreads();
  if (w == 0) {
    #pragma unroll
    for (int i = 1; i < 4; ++i) { s += ss[i][lane]; mx = fmaxf(mx, sm[i][lane]); }
    part_sum[(size_t)b * 64 + lane] = s;
    part_max[(size_t)b * 64 + lane] = mx;
  }
}

// ---------------- pool stage 2: reduce partials, write gc ----------------
// gc layout: [s_mean, t_mean, w_mean, s_max, t_max, w_max] (64 each)
__global__ void pool2_kernel(const float* __restrict__ part_sum,
                             const float* __restrict__ part_max,
                             float* __restrict__ gc) {
  int b = blockIdx.x;  // 0 station, 1 task, 2 worker
  int lane = threadIdx.x & 63, w = threadIdx.x >> 6;
  int off, cnt, N, mi;
  if (b == 0)      { off = 100; cnt = 4;  N = 1000;  mi = 0;   }
  else if (b == 1) { off = 0;   cnt = 80; N = 20000; mi = 64;  }
  else             { off = 80;  cnt = 20; N = 5000;  mi = 128; }
  float s = 0.f, mx = -3e38f;
  for (int i = w; i < cnt; i += 4) {
    s += part_sum[(size_t)(off + i) * 64 + lane];
    mx = fmaxf(mx, part_max[(size_t)(off + i) * 64 + lane]);
  }
  __shared__ float ss[4][64], sm[4][64];
  ss[w][lane] = s; sm[w][lane] = mx;
  __syncthreads();
  if (w == 0) {
    #pragma unroll
    for (int i = 1; i < 4; ++i) { s += ss[i][lane]; mx = fmaxf(mx, sm[i][lane]); }
    gc[mi + lane] = s / (float)N;
    gc[192 + mi + lane] = mx;
  }
}

// ---------------- driver ----------------
extern "C" void kernel_launch(void* const* d_in, const int* in_sizes, int n_in,
                              void* d_out, int out_size, void* d_ws, size_t ws_size,
                              hipStream_t stream) {
  const float* x_in[3] = {(const float*)d_in[0], (const float*)d_in[1], (const float*)d_in[2]};
  const int*   ei[5]   = {(const int*)d_in[3], (const int*)d_in[4], (const int*)d_in[5],
                          (const int*)d_in[6], (const int*)d_in[7]};
  const float* Wemb[3] = {(const float*)d_in[8],  (const float*)d_in[12], (const float*)d_in[16]};
  const float* bemb[3] = {(const float*)d_in[9],  (const float*)d_in[13], (const float*)d_in[17]};
  const float* gemb[3] = {(const float*)d_in[10], (const float*)d_in[14], (const float*)d_in[18]};
  const float* beemb[3]= {(const float*)d_in[11], (const float*)d_in[15], (const float*)d_in[19]};
  const float* gWl   = (const float*)d_in[20];
  const float* gWr   = (const float*)d_in[21];
  const float* gatt  = (const float*)d_in[22];
  const float* gbias = (const float*)d_in[23];

  const int NN[3]  = {20000, 5000, 1000};   // task, worker, station
  const int FD[3]  = {16, 12, 10};
  const int EC[5]  = {50000, 30000, 30000, 40000, 40000};
  const int STy[5] = {0, 0, 2, 1, 0};
  const int DTy[5] = {0, 2, 0, 0, 1};

  char* p = (char*)d_ws;
  auto alloc = [&](size_t bytes) -> void* {
    void* r = (void*)p;
    p += (bytes + 255) & ~(size_t)255;
    return r;
  };
  float* xc[3];
  for (int k = 0; k < 3; ++k) xc[k] = (float*)alloc((size_t)NN[k] * 64 * 4);
  float* aggBase = (float*)alloc((size_t)26000 * 64 * 4);
  float* agg[3] = {aggBase, aggBase + (size_t)20000 * 64, aggBase + (size_t)25000 * 64};
  float* xlb    = (float*)alloc((size_t)20000 * 256 * 4);
  float* xrb    = (float*)alloc((size_t)20000 * 256 * 4);
  float* logits = (float*)alloc((size_t)50000 * 4 * 4);
  float* psum   = (float*)alloc((size_t)104 * 64 * 4);
  float* pmax   = (float*)alloc((size_t)104 * 64 * 4);
  int *rowp[5], *nxt[5], *col[5];
  for (int t = 0; t < 5; ++t) {
    rowp[t] = (int*)alloc((size_t)(NN[DTy[t]] + 1) * 4);
    nxt[t]  = (int*)alloc((size_t)NN[DTy[t]] * 4);
    col[t]  = (int*)alloc((size_t)EC[t] * 4);
  }

  // 1) embedders
  for (int k = 0; k < 3; ++k) {
    int threads = NN[k] * 64;
    embed_kernel<<<(threads + 255) / 256, 256, 0, stream>>>(
        x_in[k], Wemb[k], bemb[k], gemb[k], beemb[k], xc[k], NN[k], FD[k]);
  }

  // 2) CSR per edge type (edges are layer-invariant)
  for (int t = 0; t < 5; ++t) {
    int Nd = NN[DTy[t]], E = EC[t];
    zero_kernel<<<64, 256, 0, stream>>>((unsigned*)nxt[t], Nd);
    count_kernel<<<(E + 255) / 256, 256, 0, stream>>>(ei[t], E, nxt[t]);
    scan_kernel<<<1, 1024, 0, stream>>>(nxt[t], rowp[t], Nd);
    fill_kernel<<<(E + 255) / 256, 256, 0, stream>>>(ei[t], E, nxt[t], col[t]);
  }

  float* outT = (float*)d_out;
  float* outW = outT + (size_t)20000 * 64;
  float* outS = outW + (size_t)5000 * 64;
  float* gc   = outS + (size_t)1000 * 64;

  // 3) GAT layers (first edge-type per dst-type overwrites agg; later accumulate)
  for (int l = 0; l < 2; ++l) {
    bool seen[3] = {false, false, false};
    for (int t = 0; t < 5; ++t) {
      int s = STy[t], dt = DTy[t];
      int Ns = NN[s], Nd = NN[dt];
      size_t off = (size_t)(l * 5 + t);
      gemm_kernel<16><<<(Ns + 15) / 16, 256, 0, stream>>>(xc[s],  gWl + off * 64 * 256, xlb, Ns);
      gemm_kernel<16><<<(Nd + 15) / 16, 256, 0, stream>>>(xc[dt], gWr + off * 64 * 256, xrb, Nd);
      gat_kernel<<<(Nd * 64 + 255) / 256, 256, 0, stream>>>(
          xlb, xrb, rowp[t], col[t], gatt + off * 256, gbias + off * 64,
          logits, agg[dt], Nd, seen[dt] ? 1 : 0);
      seen[dt] = true;
    }
    for (int k = 0; k < 3; ++k) {
      float* dst = (l == 1) ? (k == 0 ? outT : (k == 1 ? outW : outS)) : xc[k];
      int n = NN[k] * 64;
      combine_kernel<<<(n + 255) / 256, 256, 0, stream>>>(agg[k], xc[k], dst, n);
    }
  }

  // 4) global pooling (two-stage parallel)
  pool1_kernel<<<104, 256, 0, stream>>>(outT, outW, outS, psum, pmax);
  pool2_kernel<<<3, 256, 0, stream>>>(psum, pmax, gc);
}

// Round 3
// 347.794 us; speedup vs baseline: 3.7839x; 2.6742x over previous
//
#include <hip/hip_runtime.h>
#include <math.h>

#define NT 20000
#define NW 5000
#define NS 1000

// ---------------- segment tables ----------------
struct GemmSeg { const float* X; const float* W; float* Y; int N; int blk0; };
struct GemmTab { GemmSeg s[10]; int nseg; };

struct GatSeg { const int* rowp; const int* col; const float* xl; const float* xr;
                const float* att; const float* bias; float* agg; int Nd; int wave0; };
struct GatTab { GatSeg s[5]; int nseg; };

struct EdgeSeg { const int* ei; int* cnt; int* col; int E; int blk0; };
struct EdgeTab { EdgeSeg s[5]; int nseg; };

struct ScanTab { int* cnt[5]; int* rowp[5]; int n[5]; };

// ---------------- helpers ----------------
__device__ __forceinline__ float wsum64(float v) {
  #pragma unroll
  for (int o = 32; o > 0; o >>= 1) v += __shfl_xor(v, o, 64);
  return v;
}

// ---------------- embed: y = relu(LN(x@W + b) * g + beta) ----------------
__global__ void embed_kernel(const float* __restrict__ x, const float* __restrict__ W,
                             const float* __restrict__ b, const float* __restrict__ g,
                             const float* __restrict__ beta, float* __restrict__ y,
                             int N, int FD) {
  int gid  = blockIdx.x * blockDim.x + threadIdx.x;
  int wid  = gid >> 6;
  int lane = gid & 63;
  if (wid >= N) return;
  const float* xr = x + (size_t)wid * FD;
  float acc = b[lane];
  for (int k = 0; k < FD; ++k) acc = fmaf(xr[k], W[k * 64 + lane], acc);
  float m = wsum64(acc) * (1.f / 64.f);
  float d = acc - m;
  float v = wsum64(d * d) * (1.f / 64.f);
  float o = d * rsqrtf(v + 1e-5f) * g[lane] + beta[lane];
  y[(size_t)wid * 64 + lane] = fmaxf(o, 0.f);
}

// ---------------- zero ----------------
__global__ void zero_kernel(unsigned int* __restrict__ p, long long n) {
  long long i  = (long long)blockIdx.x * blockDim.x + threadIdx.x;
  long long st = (long long)gridDim.x * blockDim.x;
  for (; i < n; i += st) p[i] = 0u;
}

// ---------------- CSR: count / scan / fill (segmented) ----------------
__global__ void count_kernel(EdgeTab tab) {
  int b = blockIdx.x, si = 0;
  for (int i = 1; i < tab.nseg; ++i) if (b >= tab.s[i].blk0) si = i;
  EdgeSeg sg = tab.s[si];
  int e = (b - sg.blk0) * 256 + threadIdx.x;
  if (e < sg.E) atomicAdd(&sg.cnt[sg.ei[sg.E + e]], 1);
}

__global__ void scan_kernel(ScanTab tab) {
  int t = blockIdx.x;
  int* cnt = tab.cnt[t]; int* rowp = tab.rowp[t]; int n = tab.n[t];
  __shared__ int wsums[16];
  __shared__ int carry_s;
  int tid = threadIdx.x, lane = tid & 63, w = tid >> 6;
  if (tid == 0) carry_s = 0;
  __syncthreads();
  for (int base = 0; base < n; base += 1024) {
    int i = base + tid;
    int v = (i < n) ? cnt[i] : 0;
    int s = v;
    #pragma unroll
    for (int o = 1; o < 64; o <<= 1) { int x = __shfl_up(s, o, 64); if (lane >= o) s += x; }
    if (lane == 63) wsums[w] = s;
    __syncthreads();
    if (w == 0 && lane < 16) {
      int x = wsums[lane];
      #pragma unroll
      for (int o = 1; o < 16; o <<= 1) { int y = __shfl_up(x, o, 16); if (lane >= o) x += y; }
      wsums[lane] = x;
    }
    __syncthreads();
    int carry   = carry_s;
    int waveoff = (w == 0) ? 0 : wsums[w - 1];
    int exc     = carry + waveoff + s - v;
    if (i < n) { rowp[i] = exc; cnt[i] = exc; }
    __syncthreads();
    if (tid == 0) carry_s += wsums[15];
    __syncthreads();
  }
  if (threadIdx.x == 0) rowp[n] = carry_s;
}

__global__ void fill_kernel(EdgeTab tab) {
  int b = blockIdx.x, si = 0;
  for (int i = 1; i < tab.nseg; ++i) if (b >= tab.s[i].blk0) si = i;
  EdgeSeg sg = tab.s[si];
  int e = (b - sg.blk0) * 256 + threadIdx.x;
  if (e >= sg.E) return;
  int s = sg.ei[e], d = sg.ei[sg.E + e];
  int pos = atomicAdd(&sg.cnt[d], 1);
  sg.col[pos] = s;
}

// ---------------- GEMM: per-block 64 rows x 256 cols, thread = 16r x 4c ----------------
__global__ __launch_bounds__(256) void gemm_kernel(GemmTab tab) {
  __shared__ float Ws[64 * 256];   // [k][col] 64 KB
  __shared__ float XsT[64][64];    // [k][row] 16 KB
  int b = blockIdx.x, si = 0;
  for (int i = 1; i < tab.nseg; ++i) if (b >= tab.s[i].blk0) si = i;
  GemmSeg sg = tab.s[si];
  int r0 = (b - sg.blk0) * 64;
  int tid = threadIdx.x;
  const float4* W4 = (const float4*)sg.W;
  float4* Ws4 = (float4*)Ws;
  #pragma unroll
  for (int i = 0; i < 16; ++i) Ws4[i * 256 + tid] = W4[i * 256 + tid];
  #pragma unroll
  for (int it = 0; it < 4; ++it) {
    int idx = it * 256 + tid;
    int r = idx & 63, kq = idx >> 6;            // kq 0..15
    float4 v = make_float4(0.f, 0.f, 0.f, 0.f);
    if (r0 + r < sg.N) v = *(const float4*)&sg.X[(size_t)(r0 + r) * 64 + kq * 4];
    XsT[kq * 4 + 0][r] = v.x; XsT[kq * 4 + 1][r] = v.y;
    XsT[kq * 4 + 2][r] = v.z; XsT[kq * 4 + 3][r] = v.w;
  }
  __syncthreads();
  int colg = tid & 63, rowg = tid >> 6;
  float4 acc[16];
  #pragma unroll
  for (int j = 0; j < 16; ++j) acc[j] = make_float4(0.f, 0.f, 0.f, 0.f);
  #pragma unroll 4
  for (int k = 0; k < 64; ++k) {
    float4 w = *(const float4*)&Ws[k * 256 + colg * 4];
    const float* xp = &XsT[k][rowg * 16];
    float4 xa = *(const float4*)&xp[0];
    float4 xb = *(const float4*)&xp[4];
    float4 xc = *(const float4*)&xp[8];
    float4 xd = *(const float4*)&xp[12];
    float xv[16] = {xa.x, xa.y, xa.z, xa.w, xb.x, xb.y, xb.z, xb.w,
                    xc.x, xc.y, xc.z, xc.w, xd.x, xd.y, xd.z, xd.w};
    #pragma unroll
    for (int j = 0; j < 16; ++j) {
      acc[j].x = fmaf(xv[j], w.x, acc[j].x);
      acc[j].y = fmaf(xv[j], w.y, acc[j].y);
      acc[j].z = fmaf(xv[j], w.z, acc[j].z);
      acc[j].w = fmaf(xv[j], w.w, acc[j].w);
    }
  }
  #pragma unroll
  for (int j = 0; j < 16; ++j) {
    int row = r0 + rowg * 16 + j;
    if (row < sg.N) *(float4*)&sg.Y[(size_t)row * 256 + colg * 4] = acc[j];
  }
}

// ---------------- GATv2: wave per dst node, 4 heads x 16 lanes ----------------
__global__ void gat_kernel(GatTab tab) {
  int gwave = (blockIdx.x * blockDim.x + threadIdx.x) >> 6;
  int lane  = threadIdx.x & 63;
  int si = 0;
  for (int i = 1; i < tab.nseg; ++i) if (gwave >= tab.s[i].wave0) si = i;
  GatSeg sg = tab.s[si];
  int n = gwave - sg.wave0;
  if (n >= sg.Nd) return;
  int h = lane >> 4, lig = lane & 15;           // head, lane-in-group (4 dims each)
  int beg = sg.rowp[n], end = sg.rowp[n + 1];
  float4 xr4 = *(const float4*)&sg.xr[(size_t)n * 256 + h * 64 + lig * 4];
  float4 a4  = *(const float4*)&sg.att[h * 64 + lig * 4];
  float den = 0.f;
  float4 c = make_float4(0.f, 0.f, 0.f, 0.f);
  for (int i = beg; i < end; ++i) {
    int s = sg.col[i];
    float4 xl4 = *(const float4*)&sg.xl[(size_t)s * 256 + h * 64 + lig * 4];
    float vx = xl4.x + xr4.x, vy = xl4.y + xr4.y, vz = xl4.z + xr4.z, vw = xl4.w + xr4.w;
    vx = fmaxf(vx, 0.2f * vx); vy = fmaxf(vy, 0.2f * vy);
    vz = fmaxf(vz, 0.2f * vz); vw = fmaxf(vw, 0.2f * vw);
    float d = fmaf(vx, a4.x, fmaf(vy, a4.y, fmaf(vz, a4.z, vw * a4.w)));
    d += __shfl_xor(d, 1, 64);
    d += __shfl_xor(d, 2, 64);
    d += __shfl_xor(d, 4, 64);
    d += __shfl_xor(d, 8, 64);
    float e = __expf(d);                         // softmax is shift-invariant; logits are O(10)
    den += e;
    c.x = fmaf(e, xl4.x, c.x); c.y = fmaf(e, xl4.y, c.y);
    c.z = fmaf(e, xl4.z, c.z); c.w = fmaf(e, xl4.w, c.w);
  }
  float4 o = make_float4(0.f, 0.f, 0.f, 0.f);
  if (end > beg) {
    float inv = 1.f / den;
    o.x = c.x * inv; o.y = c.y * inv; o.z = c.z * inv; o.w = c.w * inv;
  }
  o.x += __shfl_xor(o.x, 16, 64); o.x += __shfl_xor(o.x, 32, 64);
  o.y += __shfl_xor(o.y, 16, 64); o.y += __shfl_xor(o.y, 32, 64);
  o.z += __shfl_xor(o.z, 16, 64); o.z += __shfl_xor(o.z, 32, 64);
  o.w += __shfl_xor(o.w, 16, 64); o.w += __shfl_xor(o.w, 32, 64);
  if (lane < 16) {
    float4 b4 = *(const float4*)&sg.bias[lane * 4];
    float4 res;
    res.x = fmaf(0.25f, o.x, b4.x); res.y = fmaf(0.25f, o.y, b4.y);
    res.z = fmaf(0.25f, o.z, b4.z); res.w = fmaf(0.25f, o.w, b4.w);
    *(float4*)&sg.agg[(size_t)n * 64 + lane * 4] = res;
  }
}

// ---------------- combine: out = relu(sum aggs) + x (all 3 types, 1 dispatch) ----------------
__global__ void combine_kernel(const float* __restrict__ aT0, const float* __restrict__ aT2,
                               const float* __restrict__ aT3, const float* __restrict__ aW,
                               const float* __restrict__ aS,
                               const float* __restrict__ xT, const float* __restrict__ xW,
                               const float* __restrict__ xS,
                               float* __restrict__ oT, float* __restrict__ oW,
                               float* __restrict__ oS) {
  int i = blockIdx.x * 256 + threadIdx.x;
  const int nT = NT * 64, nW = NW * 64, nS = NS * 64;
  if (i < nT) {
    oT[i] = fmaxf(aT0[i] + aT2[i] + aT3[i], 0.f) + xT[i];
  } else if (i < nT + nW) {
    int j = i - nT; oW[j] = fmaxf(aW[j], 0.f) + xW[j];
  } else if (i < nT + nW + nS) {
    int j = i - nT - nW; oS[j] = fmaxf(aS[j], 0.f) + xS[j];
  }
}

// ---------------- pool (two-stage) ----------------
__global__ __launch_bounds__(256) void pool1_kernel(const float* __restrict__ xt,
                                                    const float* __restrict__ xw,
                                                    const float* __restrict__ xs,
                                                    float* __restrict__ part_sum,
                                                    float* __restrict__ part_max) {
  int b = blockIdx.x;
  const float* x; int N, base, nb;
  if (b < 80)       { x = xt; N = NT; base = 0;   nb = 80; }
  else if (b < 100) { x = xw; N = NW; base = 80;  nb = 20; }
  else              { x = xs; N = NS; base = 100; nb = 4;  }
  int local = b - base;
  int lane = threadIdx.x & 63, w = threadIdx.x >> 6;
  int waveIdx = local * 4 + w, stride = nb * 4;
  float s = 0.f, mx = -3e38f;
  for (int r = waveIdx; r < N; r += stride) {
    float v = x[(size_t)r * 64 + lane];
    s += v; mx = fmaxf(mx, v);
  }
  __shared__ float ss[4][64], sm[4][64];
  ss[w][lane] = s; sm[w][lane] = mx;
  __syncthreads();
  if (w == 0) {
    #pragma unroll
    for (int i = 1; i < 4; ++i) { s += ss[i][lane]; mx = fmaxf(mx, sm[i][lane]); }
    part_sum[(size_t)b * 64 + lane] = s;
    part_max[(size_t)b * 64 + lane] = mx;
  }
}

__global__ void pool2_kernel(const float* __restrict__ part_sum,
                             const float* __restrict__ part_max,
                             float* __restrict__ gc) {
  int b = blockIdx.x;  // 0 station, 1 task, 2 worker
  int lane = threadIdx.x & 63, w = threadIdx.x >> 6;
  int off, cnt, N, mi;
  if (b == 0)      { off = 100; cnt = 4;  N = NS; mi = 0;   }
  else if (b == 1) { off = 0;   cnt = 80; N = NT; mi = 64;  }
  else             { off = 80;  cnt = 20; N = NW; mi = 128; }
  float s = 0.f, mx = -3e38f;
  for (int i = w; i < cnt; i += 4) {
    s += part_sum[(size_t)(off + i) * 64 + lane];
    mx = fmaxf(mx, part_max[(size_t)(off + i) * 64 + lane]);
  }
  __shared__ float ss[4][64], sm[4][64];
  ss[w][lane] = s; sm[w][lane] = mx;
  __syncthreads();
  if (w == 0) {
    #pragma unroll
    for (int i = 1; i < 4; ++i) { s += ss[i][lane]; mx = fmaxf(mx, sm[i][lane]); }
    gc[mi + lane] = s / (float)N;
    gc[192 + mi + lane] = mx;
  }
}

// ---------------- driver ----------------
extern "C" void kernel_launch(void* const* d_in, const int* in_sizes, int n_in,
                              void* d_out, int out_size, void* d_ws, size_t ws_size,
                              hipStream_t stream) {
  const float* x_in[3] = {(const float*)d_in[0], (const float*)d_in[1], (const float*)d_in[2]};
  const int*   ei[5]   = {(const int*)d_in[3], (const int*)d_in[4], (const int*)d_in[5],
                          (const int*)d_in[6], (const int*)d_in[7]};
  const float* Wemb[3] = {(const float*)d_in[8],  (const float*)d_in[12], (const float*)d_in[16]};
  const float* bemb[3] = {(const float*)d_in[9],  (const float*)d_in[13], (const float*)d_in[17]};
  const float* gemb[3] = {(const float*)d_in[10], (const float*)d_in[14], (const float*)d_in[18]};
  const float* beemb[3]= {(const float*)d_in[11], (const float*)d_in[15], (const float*)d_in[19]};
  const float* gWl   = (const float*)d_in[20];
  const float* gWr   = (const float*)d_in[21];
  const float* gatt  = (const float*)d_in[22];
  const float* gbias = (const float*)d_in[23];

  const int NN[3]  = {NT, NW, NS};
  const int FD[3]  = {16, 12, 10};
  const int EC[5]  = {50000, 30000, 30000, 40000, 40000};
  const int STy[5] = {0, 0, 2, 1, 0};
  const int DTy[5] = {0, 2, 0, 0, 1};

  char* p = (char*)d_ws;
  auto alloc = [&](size_t bytes) -> void* {
    void* r = (void*)p;
    p += (bytes + 255) & ~(size_t)255;
    return r;
  };
  float* xc[3];
  for (int k = 0; k < 3; ++k) xc[k] = (float*)alloc((size_t)NN[k] * 64 * 4);
  // per-edge-type agg slices (t0->task, t1->station, t2->task, t3->task, t4->worker)
  float* aggT0 = (float*)alloc((size_t)NT * 64 * 4);
  float* aggS  = (float*)alloc((size_t)NS * 64 * 4);
  float* aggT2 = (float*)alloc((size_t)NT * 64 * 4);
  float* aggT3 = (float*)alloc((size_t)NT * 64 * 4);
  float* aggW  = (float*)alloc((size_t)NW * 64 * 4);
  float* aggOf[5] = {aggT0, aggS, aggT2, aggT3, aggW};
  int* nxtAll = (int*)alloc((size_t)66000 * 4);
  int  nxtOff[5] = {0, NT, NT + NS, 2 * NT + NS, 3 * NT + NS};
  int* nxt[5]; for (int t = 0; t < 5; ++t) nxt[t] = nxtAll + nxtOff[t];
  int *rowp[5], *col[5];
  for (int t = 0; t < 5; ++t) {
    rowp[t] = (int*)alloc((size_t)(NN[DTy[t]] + 1) * 4);
    col[t]  = (int*)alloc((size_t)EC[t] * 4);
  }
  float* psum = (float*)alloc((size_t)104 * 64 * 4);
  float* pmax = (float*)alloc((size_t)104 * 64 * 4);

  // xl/xr buffers: per-type (fused, ~135MB) if ws allows, else shared (~41MB)
  size_t used = (size_t)(p - (char*)d_ws);
  size_t fusedExtra = (size_t)132000 * 256 * 4 + (1 << 20);
  bool fused = (ws_size - used) >= fusedExtra;
  float *xlT[5], *xrT[5];
  if (fused) {
    for (int t = 0; t < 5; ++t) {
      xlT[t] = (float*)alloc((size_t)NN[STy[t]] * 256 * 4);
      xrT[t] = (float*)alloc((size_t)NN[DTy[t]] * 256 * 4);
    }
  } else {
    float* xlb = (float*)alloc((size_t)NT * 256 * 4);
    float* xrb = (float*)alloc((size_t)NT * 256 * 4);
    for (int t = 0; t < 5; ++t) { xlT[t] = xlb; xrT[t] = xrb; }
  }

  // 1) embedders
  for (int k = 0; k < 3; ++k) {
    int threads = NN[k] * 64;
    embed_kernel<<<(threads + 255) / 256, 256, 0, stream>>>(
        x_in[k], Wemb[k], bemb[k], gemb[k], beemb[k], xc[k], NN[k], FD[k]);
  }

  // 2) CSR (4 dispatches)
  zero_kernel<<<64, 256, 0, stream>>>((unsigned*)nxtAll, 66000);
  EdgeTab etab; etab.nseg = 5;
  int eb = 0;
  for (int t = 0; t < 5; ++t) {
    etab.s[t] = {ei[t], nxt[t], col[t], EC[t], eb};
    eb += (EC[t] + 255) / 256;
  }
  count_kernel<<<eb, 256, 0, stream>>>(etab);
  ScanTab stab;
  for (int t = 0; t < 5; ++t) { stab.cnt[t] = nxt[t]; stab.rowp[t] = rowp[t]; stab.n[t] = NN[DTy[t]]; }
  scan_kernel<<<5, 1024, 0, stream>>>(stab);
  fill_kernel<<<eb, 256, 0, stream>>>(etab);

  float* outT = (float*)d_out;
  float* outW = outT + (size_t)NT * 64;
  float* outS = outW + (size_t)NW * 64;
  float* gc   = outS + (size_t)NS * 64;

  // 3) GAT layers
  for (int l = 0; l < 2; ++l) {
    if (fused) {
      GemmTab gt; gt.nseg = 10;
      int gb = 0;
      for (int t = 0; t < 5; ++t) {
        size_t off = (size_t)(l * 5 + t);
        gt.s[2 * t + 0] = {xc[STy[t]], gWl + off * 16384, xlT[t], NN[STy[t]], gb};
        gb += (NN[STy[t]] + 63) / 64;
        gt.s[2 * t + 1] = {xc[DTy[t]], gWr + off * 16384, xrT[t], NN[DTy[t]], gb};
        gb += (NN[DTy[t]] + 63) / 64;
      }
      gemm_kernel<<<gb, 256, 0, stream>>>(gt);

      GatTab at; at.nseg = 5;
      int wv = 0;
      for (int t = 0; t < 5; ++t) {
        size_t off = (size_t)(l * 5 + t);
        at.s[t] = {rowp[t], col[t], xlT[t], xrT[t], gatt + off * 256, gbias + off * 64,
                   aggOf[t], NN[DTy[t]], wv};
        wv += NN[DTy[t]];
      }
      gat_kernel<<<(wv * 64 + 255) / 256, 256, 0, stream>>>(at);
    } else {
      for (int t = 0; t < 5; ++t) {
        size_t off = (size_t)(l * 5 + t);
        GemmTab gt; gt.nseg = 2;
        gt.s[0] = {xc[STy[t]], gWl + off * 16384, xlT[t], NN[STy[t]], 0};
        int gb = (NN[STy[t]] + 63) / 64;
        gt.s[1] = {xc[DTy[t]], gWr + off * 16384, xrT[t], NN[DTy[t]], gb};
        gb += (NN[DTy[t]] + 63) / 64;
        gemm_kernel<<<gb, 256, 0, stream>>>(gt);
        GatTab at; at.nseg = 1;
        at.s[0] = {rowp[t], col[t], xlT[t], xrT[t], gatt + off * 256, gbias + off * 64,
                   aggOf[t], NN[DTy[t]], 0};
        gat_kernel<<<((NN[DTy[t]] + 3) / 4), 256, 0, stream>>>(at);
      }
    }
    float* dT = (l == 1) ? outT : xc[0];
    float* dW = (l == 1) ? outW : xc[1];
    float* dS = (l == 1) ? outS : xc[2];
    combine_kernel<<<(26000 * 64 + 255) / 256, 256, 0, stream>>>(
        aggT0, aggT2, aggT3, aggW, aggS, xc[0], xc[1], xc[2], dT, dW, dS);
  }

  // 4) global pooling
  pool1_kernel<<<104, 256, 0, stream>>>(outT, outW, outS, psum, pmax);
  pool2_kernel<<<3, 256, 0, stream>>>(psum, pmax, gc);
}

// Round 4
// 240.488 us; speedup vs baseline: 5.4723x; 1.4462x over previous
//
#include <hip/hip_runtime.h>
#include <math.h>

#define NT 20000
#define NW 5000
#define NS 1000

typedef __attribute__((ext_vector_type(8))) short bf16x8;
typedef __attribute__((ext_vector_type(4))) float f32x4;

// ---------------- segment tables ----------------
struct GemmSeg { const short* X; const short* Wt; short* Y; int N; int blk0; };
struct GemmTab { GemmSeg s[10]; int nseg; };

struct GatSeg { const int* rowp; const int* col; const short* xl; const short* xr;
                const float* att; const float* bias; float* agg; int Nd; int wave0; };
struct GatTab { GatSeg s[5]; int nseg; };

struct EdgeSeg { const int* ei; int* cnt; int* col; int E; int blk0; };
struct EdgeTab { EdgeSeg s[5]; int nseg; };

struct ScanTab { int* cnt[5]; int* rowp[5]; int n[5]; };

// ---------------- helpers ----------------
__device__ __forceinline__ float wsum64(float v) {
  #pragma unroll
  for (int o = 32; o > 0; o >>= 1) v += __shfl_xor(v, o, 64);
  return v;
}
__device__ __forceinline__ short f2b(float f) {   // f32 -> bf16 RNE
  unsigned u = __float_as_uint(f);
  unsigned r = (u + 0x7FFFu + ((u >> 16) & 1u)) >> 16;
  return (short)(unsigned short)r;
}
__device__ __forceinline__ float blo(unsigned x) { return __uint_as_float(x << 16); }
__device__ __forceinline__ float bhi(unsigned x) { return __uint_as_float(x & 0xFFFF0000u); }

// ---------------- weight prep: f32 [k][col] -> bf16 [col][k], 20 matrices/side ----------------
__global__ void wprep_kernel(const float* __restrict__ gWl, const float* __restrict__ gWr,
                             short* __restrict__ Wlt, short* __restrict__ Wrt) {
  int idx = blockIdx.x * 256 + threadIdx.x;           // 0 .. 327679
  int side = idx >= 163840;
  int j = idx - side * 163840;
  int m = j >> 14;                                    // matrix 0..9
  int e = j & 16383;
  int k = e >> 8, colv = e & 255;
  const float* src = side ? gWr : gWl;
  short* dst = side ? Wrt : Wlt;
  dst[m * 16384 + colv * 64 + k] = f2b(src[m * 16384 + e]);
}

// ---------------- embed: y = relu(LN(x@W + b) * g + beta), f32 + bf16 outputs --------
__global__ void embed_kernel(const float* __restrict__ x, const float* __restrict__ W,
                             const float* __restrict__ b, const float* __restrict__ g,
                             const float* __restrict__ beta, float* __restrict__ y,
                             short* __restrict__ yb, int N, int FD) {
  int gid  = blockIdx.x * blockDim.x + threadIdx.x;
  int wid  = gid >> 6;
  int lane = gid & 63;
  if (wid >= N) return;
  const float* xr = x + (size_t)wid * FD;
  float acc = b[lane];
  for (int k = 0; k < FD; ++k) acc = fmaf(xr[k], W[k * 64 + lane], acc);
  float m = wsum64(acc) * (1.f / 64.f);
  float d = acc - m;
  float v = wsum64(d * d) * (1.f / 64.f);
  float o = d * rsqrtf(v + 1e-5f) * g[lane] + beta[lane];
  o = fmaxf(o, 0.f);
  y[(size_t)wid * 64 + lane] = o;
  yb[(size_t)wid * 64 + lane] = f2b(o);
}

// ---------------- zero ----------------
__global__ void zero_kernel(unsigned int* __restrict__ p, long long n) {
  long long i  = (long long)blockIdx.x * blockDim.x + threadIdx.x;
  long long st = (long long)gridDim.x * blockDim.x;
  for (; i < n; i += st) p[i] = 0u;
}

// ---------------- CSR: count / scan / fill (segmented) ----------------
__global__ void count_kernel(EdgeTab tab) {
  int b = blockIdx.x, si = 0;
  for (int i = 1; i < tab.nseg; ++i) if (b >= tab.s[i].blk0) si = i;
  EdgeSeg sg = tab.s[si];
  int e = (b - sg.blk0) * 256 + threadIdx.x;
  if (e < sg.E) atomicAdd(&sg.cnt[sg.ei[sg.E + e]], 1);
}

__global__ void scan_kernel(ScanTab tab) {
  int t = blockIdx.x;
  int* cnt = tab.cnt[t]; int* rowp = tab.rowp[t]; int n = tab.n[t];
  __shared__ int wsums[16];
  __shared__ int carry_s;
  int tid = threadIdx.x, lane = tid & 63, w = tid >> 6;
  if (tid == 0) carry_s = 0;
  __syncthreads();
  for (int base = 0; base < n; base += 1024) {
    int i = base + tid;
    int v = (i < n) ? cnt[i] : 0;
    int s = v;
    #pragma unroll
    for (int o = 1; o < 64; o <<= 1) { int x = __shfl_up(s, o, 64); if (lane >= o) s += x; }
    if (lane == 63) wsums[w] = s;
    __syncthreads();
    if (w == 0 && lane < 16) {
      int x = wsums[lane];
      #pragma unroll
      for (int o = 1; o < 16; o <<= 1) { int y = __shfl_up(x, o, 16); if (lane >= o) x += y; }
      wsums[lane] = x;
    }
    __syncthreads();
    int carry   = carry_s;
    int waveoff = (w == 0) ? 0 : wsums[w - 1];
    int exc     = carry + waveoff + s - v;
    if (i < n) { rowp[i] = exc; cnt[i] = exc; }
    __syncthreads();
    if (tid == 0) carry_s += wsums[15];
    __syncthreads();
  }
  if (threadIdx.x == 0) rowp[n] = carry_s;
}

__global__ void fill_kernel(EdgeTab tab) {
  int b = blockIdx.x, si = 0;
  for (int i = 1; i < tab.nseg; ++i) if (b >= tab.s[i].blk0) si = i;
  EdgeSeg sg = tab.s[si];
  int e = (b - sg.blk0) * 256 + threadIdx.x;
  if (e >= sg.E) return;
  int s = sg.ei[e], d = sg.ei[sg.E + e];
  int pos = atomicAdd(&sg.cnt[d], 1);
  sg.col[pos] = s;
}

// ---------------- MFMA GEMM: Y[N,256](bf16) = X[N,64](bf16) @ W[64,256] ----------------
// block = 256 thr = 4 waves; tile 64 rows x 256 cols; wave = 64-col stripe.
// LDS: Xs[64][64] + WsT[256][64] bf16, XOR-swizzled in 16B units.
__global__ __launch_bounds__(256) void gemm_kernel(GemmTab tab) {
  __shared__ short lds[4096 + 16384];   // 40 KB
  int b = blockIdx.x, si = 0;
  for (int i = 1; i < tab.nseg; ++i) if (b >= tab.s[i].blk0) si = i;
  GemmSeg sg = tab.s[si];
  int r0 = (b - sg.blk0) * 64;
  int tid = threadIdx.x;
  #pragma unroll
  for (int it = 0; it < 2; ++it) {              // stage X tile (8 KB)
    int idx = it * 256 + tid;                   // 0..511
    int row = idx >> 3, kq = idx & 7;
    bf16x8 v = {0, 0, 0, 0, 0, 0, 0, 0};
    if (r0 + row < sg.N) v = *(const bf16x8*)&sg.X[(size_t)(r0 + row) * 64 + kq * 8];
    *(bf16x8*)&lds[(row * 8 + (kq ^ (row & 7))) * 8] = v;
  }
  #pragma unroll
  for (int it = 0; it < 8; ++it) {              // stage Wt (32 KB)
    int idx = it * 256 + tid;                   // 0..2047
    int col = idx >> 3, kq = idx & 7;
    bf16x8 v = *(const bf16x8*)&sg.Wt[col * 64 + kq * 8];
    *(bf16x8*)&lds[4096 + (col * 8 + (kq ^ (col & 7))) * 8] = v;
  }
  __syncthreads();
  int lane = tid & 63, wv = tid >> 6;
  int r = lane & 15, hk = lane >> 4;            // row/col-in-tile, k-quarter
  f32x4 acc[4][4];
  #pragma unroll
  for (int rt = 0; rt < 4; ++rt)
    #pragma unroll
    for (int ct = 0; ct < 4; ++ct) acc[rt][ct] = (f32x4){0.f, 0.f, 0.f, 0.f};
  #pragma unroll
  for (int kk = 0; kk < 2; ++kk) {
    int kq = kk * 4 + hk;
    bf16x8 a[4], bb[4];
    #pragma unroll
    for (int rt = 0; rt < 4; ++rt) {
      int row = rt * 16 + r;
      a[rt] = *(const bf16x8*)&lds[(row * 8 + (kq ^ (row & 7))) * 8];
    }
    #pragma unroll
    for (int ct = 0; ct < 4; ++ct) {
      int col = wv * 64 + ct * 16 + r;
      bb[ct] = *(const bf16x8*)&lds[4096 + (col * 8 + (kq ^ (col & 7))) * 8];
    }
    #pragma unroll
    for (int rt = 0; rt < 4; ++rt)
      #pragma unroll
      for (int ct = 0; ct < 4; ++ct)
        acc[rt][ct] = __builtin_amdgcn_mfma_f32_16x16x32_bf16(a[rt], bb[ct], acc[rt][ct], 0, 0, 0);
  }
  #pragma unroll
  for (int rt = 0; rt < 4; ++rt) {
    #pragma unroll
    for (int j = 0; j < 4; ++j) {
      int row = r0 + rt * 16 + hk * 4 + j;      // C/D: col=lane&15, row=(lane>>4)*4+reg
      if (row < sg.N) {
        #pragma unroll
        for (int ct = 0; ct < 4; ++ct) {
          int col = wv * 64 + ct * 16 + r;
          sg.Y[(size_t)row * 256 + col] = f2b(acc[rt][ct][j]);
        }
      }
    }
  }
}

// ---------------- GATv2: wave per dst node, 4 heads x 16 lanes, bf16 xl/xr ----------------
__global__ void gat_kernel(GatTab tab) {
  int gwave = (blockIdx.x * blockDim.x + threadIdx.x) >> 6;
  int lane  = threadIdx.x & 63;
  int si = 0;
  for (int i = 1; i < tab.nseg; ++i) if (gwave >= tab.s[i].wave0) si = i;
  GatSeg sg = tab.s[si];
  int n = gwave - sg.wave0;
  if (n >= sg.Nd) return;
  int h = lane >> 4, lig = lane & 15;
  int beg = sg.rowp[n], end = sg.rowp[n + 1];
  uint2 xru = *(const uint2*)&sg.xr[(size_t)n * 256 + h * 64 + lig * 4];
  float xr0 = blo(xru.x), xr1 = bhi(xru.x), xr2 = blo(xru.y), xr3 = bhi(xru.y);
  float4 a4 = *(const float4*)&sg.att[h * 64 + lig * 4];
  float den = 0.f, c0 = 0.f, c1 = 0.f, c2 = 0.f, c3 = 0.f;
  if (end > beg) {
    int sNxt = sg.col[beg];
    uint2 w = *(const uint2*)&sg.xl[(size_t)sNxt * 256 + h * 64 + lig * 4];
    if (beg + 1 < end) sNxt = sg.col[beg + 1];
    for (int i = beg; i < end; ++i) {
      uint2 wc = w;
      if (i + 1 < end)
        w = *(const uint2*)&sg.xl[(size_t)sNxt * 256 + h * 64 + lig * 4];
      if (i + 2 < end) sNxt = sg.col[i + 2];
      float f0 = blo(wc.x), f1 = bhi(wc.x), f2v = blo(wc.y), f3 = bhi(wc.y);
      float vx = f0 + xr0, vy = f1 + xr1, vz = f2v + xr2, vw = f3 + xr3;
      vx = fmaxf(vx, 0.2f * vx); vy = fmaxf(vy, 0.2f * vy);
      vz = fmaxf(vz, 0.2f * vz); vw = fmaxf(vw, 0.2f * vw);
      float d = fmaf(vx, a4.x, fmaf(vy, a4.y, fmaf(vz, a4.z, vw * a4.w)));
      d += __shfl_xor(d, 1, 64);
      d += __shfl_xor(d, 2, 64);
      d += __shfl_xor(d, 4, 64);
      d += __shfl_xor(d, 8, 64);
      float e = __expf(d);                      // softmax shift-invariant; logits O(10)
      den += e;
      c0 = fmaf(e, f0, c0); c1 = fmaf(e, f1, c1);
      c2 = fmaf(e, f2v, c2); c3 = fmaf(e, f3, c3);
    }
  }
  float4 o = make_float4(0.f, 0.f, 0.f, 0.f);
  if (end > beg) {
    float inv = 1.f / den;
    o.x = c0 * inv; o.y = c1 * inv; o.z = c2 * inv; o.w = c3 * inv;
  }
  o.x += __shfl_xor(o.x, 16, 64); o.x += __shfl_xor(o.x, 32, 64);
  o.y += __shfl_xor(o.y, 16, 64); o.y += __shfl_xor(o.y, 32, 64);
  o.z += __shfl_xor(o.z, 16, 64); o.z += __shfl_xor(o.z, 32, 64);
  o.w += __shfl_xor(o.w, 16, 64); o.w += __shfl_xor(o.w, 32, 64);
  if (lane < 16) {
    float4 b4 = *(const float4*)&sg.bias[lane * 4];
    float4 res;
    res.x = fmaf(0.25f, o.x, b4.x); res.y = fmaf(0.25f, o.y, b4.y);
    res.z = fmaf(0.25f, o.z, b4.z); res.w = fmaf(0.25f, o.w, b4.w);
    *(float4*)&sg.agg[(size_t)n * 64 + lane * 4] = res;
  }
}

// ---------------- combine: out = relu(sum aggs) + x, f32 (+ optional bf16 copy) --------
__global__ void combine_kernel(const float* __restrict__ aT0, const float* __restrict__ aT2,
                               const float* __restrict__ aT3, const float* __restrict__ aW,
                               const float* __restrict__ aS,
                               const float* __restrict__ xT, const float* __restrict__ xW,
                               const float* __restrict__ xS,
                               float* __restrict__ oT, float* __restrict__ oW,
                               float* __restrict__ oS,
                               short* __restrict__ bT, short* __restrict__ bW,
                               short* __restrict__ bS) {
  int i = blockIdx.x * 256 + threadIdx.x;
  const int nT = NT * 64, nW = NW * 64, nS = NS * 64;
  if (i < nT) {
    float v = fmaxf(aT0[i] + aT2[i] + aT3[i], 0.f) + xT[i];
    oT[i] = v; if (bT) bT[i] = f2b(v);
  } else if (i < nT + nW) {
    int j = i - nT;
    float v = fmaxf(aW[j], 0.f) + xW[j];
    oW[j] = v; if (bW) bW[j] = f2b(v);
  } else if (i < nT + nW + nS) {
    int j = i - nT - nW;
    float v = fmaxf(aS[j], 0.f) + xS[j];
    oS[j] = v; if (bS) bS[j] = f2b(v);
  }
}

// ---------------- pool (two-stage) ----------------
__global__ __launch_bounds__(256) void pool1_kernel(const float* __restrict__ xt,
                                                    const float* __restrict__ xw,
                                                    const float* __restrict__ xs,
                                                    float* __restrict__ part_sum,
                                                    float* __restrict__ part_max) {
  int b = blockIdx.x;
  const float* x; int N, base, nb;
  if (b < 80)       { x = xt; N = NT; base = 0;   nb = 80; }
  else if (b < 100) { x = xw; N = NW; base = 80;  nb = 20; }
  else              { x = xs; N = NS; base = 100; nb = 4;  }
  int local = b - base;
  int lane = threadIdx.x & 63, w = threadIdx.x >> 6;
  int waveIdx = local * 4 + w, stride = nb * 4;
  float s = 0.f, mx = -3e38f;
  for (int r = waveIdx; r < N; r += stride) {
    float v = x[(size_t)r * 64 + lane];
    s += v; mx = fmaxf(mx, v);
  }
  __shared__ float ss[4][64], sm[4][64];
  ss[w][lane] = s; sm[w][lane] = mx;
  __syncthreads();
  if (w == 0) {
    #pragma unroll
    for (int i = 1; i < 4; ++i) { s += ss[i][lane]; mx = fmaxf(mx, sm[i][lane]); }
    part_sum[(size_t)b * 64 + lane] = s;
    part_max[(size_t)b * 64 + lane] = mx;
  }
}

__global__ void pool2_kernel(const float* __restrict__ part_sum,
                             const float* __restrict__ part_max,
                             float* __restrict__ gc) {
  int b = blockIdx.x;  // 0 station, 1 task, 2 worker
  int lane = threadIdx.x & 63, w = threadIdx.x >> 6;
  int off, cnt, N, mi;
  if (b == 0)      { off = 100; cnt = 4;  N = NS; mi = 0;   }
  else if (b == 1) { off = 0;   cnt = 80; N = NT; mi = 64;  }
  else             { off = 80;  cnt = 20; N = NW; mi = 128; }
  float s = 0.f, mx = -3e38f;
  for (int i = w; i < cnt; i += 4) {
    s += part_sum[(size_t)(off + i) * 64 + lane];
    mx = fmaxf(mx, part_max[(size_t)(off + i) * 64 + lane]);
  }
  __shared__ float ss[4][64], sm[4][64];
  ss[w][lane] = s; sm[w][lane] = mx;
  __syncthreads();
  if (w == 0) {
    #pragma unroll
    for (int i = 1; i < 4; ++i) { s += ss[i][lane]; mx = fmaxf(mx, sm[i][lane]); }
    gc[mi + lane] = s / (float)N;
    gc[192 + mi + lane] = mx;
  }
}

// ---------------- driver ----------------
extern "C" void kernel_launch(void* const* d_in, const int* in_sizes, int n_in,
                              void* d_out, int out_size, void* d_ws, size_t ws_size,
                              hipStream_t stream) {
  const float* x_in[3] = {(const float*)d_in[0], (const float*)d_in[1], (const float*)d_in[2]};
  const int*   ei[5]   = {(const int*)d_in[3], (const int*)d_in[4], (const int*)d_in[5],
                          (const int*)d_in[6], (const int*)d_in[7]};
  const float* Wemb[3] = {(const float*)d_in[8],  (const float*)d_in[12], (const float*)d_in[16]};
  const float* bemb[3] = {(const float*)d_in[9],  (const float*)d_in[13], (const float*)d_in[17]};
  const float* gemb[3] = {(const float*)d_in[10], (const float*)d_in[14], (const float*)d_in[18]};
  const float* beemb[3]= {(const float*)d_in[11], (const float*)d_in[15], (const float*)d_in[19]};
  const float* gWl   = (const float*)d_in[20];
  const float* gWr   = (const float*)d_in[21];
  const float* gatt  = (const float*)d_in[22];
  const float* gbias = (const float*)d_in[23];

  const int NN[3]  = {NT, NW, NS};
  const int FD[3]  = {16, 12, 10};
  const int EC[5]  = {50000, 30000, 30000, 40000, 40000};
  const int STy[5] = {0, 0, 2, 1, 0};
  const int DTy[5] = {0, 2, 0, 0, 1};

  char* p = (char*)d_ws;
  auto alloc = [&](size_t bytes) -> void* {
    void* r = (void*)p;
    p += (bytes + 255) & ~(size_t)255;
    return r;
  };
  float* xc[3];  short* xcb[3];
  for (int k = 0; k < 3; ++k) xc[k]  = (float*)alloc((size_t)NN[k] * 64 * 4);
  for (int k = 0; k < 3; ++k) xcb[k] = (short*)alloc((size_t)NN[k] * 64 * 2);
  float* aggT0 = (float*)alloc((size_t)NT * 64 * 4);
  float* aggS  = (float*)alloc((size_t)NS * 64 * 4);
  float* aggT2 = (float*)alloc((size_t)NT * 64 * 4);
  float* aggT3 = (float*)alloc((size_t)NT * 64 * 4);
  float* aggW  = (float*)alloc((size_t)NW * 64 * 4);
  float* aggOf[5] = {aggT0, aggS, aggT2, aggT3, aggW};
  int* nxtAll = (int*)alloc((size_t)66000 * 4);
  int  nxtOff[5] = {0, NT, NT + NS, 2 * NT + NS, 3 * NT + NS};
  int* nxt[5]; for (int t = 0; t < 5; ++t) nxt[t] = nxtAll + nxtOff[t];
  int *rowp[5], *col[5];
  for (int t = 0; t < 5; ++t) {
    rowp[t] = (int*)alloc((size_t)(NN[DTy[t]] + 1) * 4);
    col[t]  = (int*)alloc((size_t)EC[t] * 4);
  }
  float* psum = (float*)alloc((size_t)104 * 64 * 4);
  float* pmax = (float*)alloc((size_t)104 * 64 * 4);
  short* Wlt  = (short*)alloc((size_t)10 * 16384 * 2);
  short* Wrt  = (short*)alloc((size_t)10 * 16384 * 2);

  size_t used = (size_t)(p - (char*)d_ws);
  size_t fusedExtra = (size_t)132000 * 256 * 2 + (1 << 20);
  bool fused = (ws_size - used) >= fusedExtra;
  short *xlT[5], *xrT[5];
  if (fused) {
    for (int t = 0; t < 5; ++t) {
      xlT[t] = (short*)alloc((size_t)NN[STy[t]] * 256 * 2);
      xrT[t] = (short*)alloc((size_t)NN[DTy[t]] * 256 * 2);
    }
  } else {
    short* xlb = (short*)alloc((size_t)NT * 256 * 2);
    short* xrb = (short*)alloc((size_t)NT * 256 * 2);
    for (int t = 0; t < 5; ++t) { xlT[t] = xlb; xrT[t] = xrb; }
  }

  // 0) weight prep (bf16 + transpose)
  wprep_kernel<<<1280, 256, 0, stream>>>(gWl, gWr, Wlt, Wrt);

  // 1) embedders
  for (int k = 0; k < 3; ++k) {
    int threads = NN[k] * 64;
    embed_kernel<<<(threads + 255) / 256, 256, 0, stream>>>(
        x_in[k], Wemb[k], bemb[k], gemb[k], beemb[k], xc[k], xcb[k], NN[k], FD[k]);
  }

  // 2) CSR (4 dispatches)
  zero_kernel<<<64, 256, 0, stream>>>((unsigned*)nxtAll, 66000);
  EdgeTab etab; etab.nseg = 5;
  int eb = 0;
  for (int t = 0; t < 5; ++t) {
    etab.s[t] = {ei[t], nxt[t], col[t], EC[t], eb};
    eb += (EC[t] + 255) / 256;
  }
  count_kernel<<<eb, 256, 0, stream>>>(etab);
  ScanTab stab;
  for (int t = 0; t < 5; ++t) { stab.cnt[t] = nxt[t]; stab.rowp[t] = rowp[t]; stab.n[t] = NN[DTy[t]]; }
  scan_kernel<<<5, 1024, 0, stream>>>(stab);
  fill_kernel<<<eb, 256, 0, stream>>>(etab);

  float* outT = (float*)d_out;
  float* outW = outT + (size_t)NT * 64;
  float* outS = outW + (size_t)NW * 64;
  float* gc   = outS + (size_t)NS * 64;

  // 3) GAT layers
  for (int l = 0; l < 2; ++l) {
    if (fused) {
      GemmTab gt; gt.nseg = 10;
      int gb = 0;
      for (int t = 0; t < 5; ++t) {
        size_t off = (size_t)(l * 5 + t);
        gt.s[2 * t + 0] = {xcb[STy[t]], Wlt + off * 16384, xlT[t], NN[STy[t]], gb};
        gb += (NN[STy[t]] + 63) / 64;
        gt.s[2 * t + 1] = {xcb[DTy[t]], Wrt + off * 16384, xrT[t], NN[DTy[t]], gb};
        gb += (NN[DTy[t]] + 63) / 64;
      }
      gemm_kernel<<<gb, 256, 0, stream>>>(gt);

      GatTab at; at.nseg = 5;
      int wv = 0;
      for (int t = 0; t < 5; ++t) {
        size_t off = (size_t)(l * 5 + t);
        at.s[t] = {rowp[t], col[t], xlT[t], xrT[t], gatt + off * 256, gbias + off * 64,
                   aggOf[t], NN[DTy[t]], wv};
        wv += NN[DTy[t]];
      }
      gat_kernel<<<(wv * 64 + 255) / 256, 256, 0, stream>>>(at);
    } else {
      for (int t = 0; t < 5; ++t) {
        size_t off = (size_t)(l * 5 + t);
        GemmTab gt; gt.nseg = 2;
        gt.s[0] = {xcb[STy[t]], Wlt + off * 16384, xlT[t], NN[STy[t]], 0};
        int gb = (NN[STy[t]] + 63) / 64;
        gt.s[1] = {xcb[DTy[t]], Wrt + off * 16384, xrT[t], NN[DTy[t]], gb};
        gb += (NN[DTy[t]] + 63) / 64;
        gemm_kernel<<<gb, 256, 0, stream>>>(gt);
        GatTab at; at.nseg = 1;
        at.s[0] = {rowp[t], col[t], xlT[t], xrT[t], gatt + off * 256, gbias + off * 64,
                   aggOf[t], NN[DTy[t]], 0};
        gat_kernel<<<((NN[DTy[t]] + 3) / 4), 256, 0, stream>>>(at);
      }
    }
    float* dT = (l == 1) ? outT : xc[0];
    float* dW = (l == 1) ? outW : xc[1];
    float* dS = (l == 1) ? outS : xc[2];
    short* bT = (l == 1) ? nullptr : xcb[0];
    short* bW = (l == 1) ? nullptr : xcb[1];
    short* bS = (l == 1) ? nullptr : xcb[2];
    combine_kernel<<<(26000 * 64 + 255) / 256, 256, 0, stream>>>(
        aggT0, aggT2, aggT3, aggW, aggS, xc[0], xc[1], xc[2], dT, dW, dS, bT, bW, bS);
  }

  // 4) global pooling
  pool1_kernel<<<104, 256, 0, stream>>>(outT, outW, outS, psum, pmax);
  pool2_kernel<<<3, 256, 0, stream>>>(psum, pmax, gc);
}